// Round 4
// baseline (19538.013 us; speedup 1.0000x reference)
//
#include <hip/hip_runtime.h>
#include <math.h>

// ---------------------------------------------------------------------------
// VAE_14482629722138 — round 4: persistent cooperative encoder/decoder kernels
// with device-scope grid barriers + double-buffered MFMA K-loop.
// B=512, T=64, CF=512, ZD=128, TDIM=520.
// ---------------------------------------------------------------------------

#define B 512
#define TT 64
#define CF 512
#define G4 2048
#define ZD 128
#define TDIM 520

typedef unsigned short u16;
typedef short bf16x8 __attribute__((ext_vector_type(8)));
typedef float f32x4 __attribute__((ext_vector_type(4)));

__device__ __forceinline__ float sigm(float x) { return 1.f / (1.f + expf(-x)); }
__device__ __forceinline__ u16 f2bf(float f) {
    unsigned u = __float_as_uint(f);
    u += 0x7fffu + ((u >> 16) & 1u);
    return (u16)(u >> 16);
}
__device__ __forceinline__ float bf2f(u16 s) { return __uint_as_float(((unsigned)s) << 16); }

// ---------------------------------------------------------------------------
// Device-scope grid barrier (sense via generation counter). All 256 blocks
// must be co-resident (cooperative launch guarantees this). Spin capped so a
// pathological failure produces wrong output instead of a hang.
// ---------------------------------------------------------------------------
__device__ __forceinline__ void gbar(unsigned* cnt, unsigned* gen, unsigned nb) {
    __syncthreads();
    if (threadIdx.x == 0) {
        __threadfence();  // release: make this block's writes visible device-wide
        unsigned g = __hip_atomic_load(gen, __ATOMIC_RELAXED, __HIP_MEMORY_SCOPE_AGENT);
        unsigned a = __hip_atomic_fetch_add(cnt, 1u, __ATOMIC_ACQ_REL, __HIP_MEMORY_SCOPE_AGENT);
        if (a == nb - 1u) {
            __hip_atomic_store(cnt, 0u, __ATOMIC_RELAXED, __HIP_MEMORY_SCOPE_AGENT);
            __hip_atomic_store(gen, g + 1u, __ATOMIC_RELEASE, __HIP_MEMORY_SCOPE_AGENT);
        } else {
            long spins = 0;
            while (__hip_atomic_load(gen, __ATOMIC_ACQUIRE, __HIP_MEMORY_SCOPE_AGENT) == g) {
                if (++spins > 8000000L) break;
            }
        }
        __threadfence();  // acquire: invalidate stale lines before next phase reads
    }
    __syncthreads();
}

// ---------------------------------------------------------------------------
// Shared-memory layout for the MFMA gemm+cell phase (double-buffered).
// ---------------------------------------------------------------------------
struct __align__(16) GemmShared {
    u16 A[2][2][64][40];   // [dbuf][hi/lo][row][k(+pad)]
    u16 Bw[2][2][64][40];
};

// ---------------------------------------------------------------------------
// MFMA GEMM + fused LSTM cell, one 64x64 tile per block (bx: cell group,
// by: batch rows). W rows gate-grouped: block bx owns cells bx*16..+16, all 4
// gates as its 4 n-subtiles. hi/lo bf16 split: 3 MFMAs per fragment pair.
// Double-buffered LDS: prefetch k+1 into regs during MFMA of k.
// Epilogue: LSTM cell -> c update, h -> next X (hi/lo bf16), optional fp32 h,
// encoder tcat capture + next-step x staging.
// ---------------------------------------------------------------------------
__device__ __forceinline__ void gemm_cell_phase(
    GemmShared& sh,
    const u16* __restrict__ Xhi, const u16* __restrict__ Xlo, int ldx,
    const u16* __restrict__ Whi, const u16* __restrict__ Wlo, int K,
    const float* __restrict__ base,    // [512][2048] permuted cols, or null
    const float* __restrict__ biaspk,  // [2048] permuted, or null
    float* __restrict__ c,             // [512][512]
    u16* __restrict__ Xnhi, u16* __restrict__ Xnlo, int ldxn, int hcol0,
    float* __restrict__ hfp,
    float* __restrict__ tcat, const int* __restrict__ lens, int t,
    const int* __restrict__ acts, const float* __restrict__ tsv,
    const float* __restrict__ act_emb,
    int bx, int by)
{
    const int tid = threadIdx.x;
    const int lane = tid & 63, ws = tid >> 6;
    const int fr = lane & 15;
    const int quad = lane >> 4;
    const int ko = quad << 3;
    const int row0 = by << 6;
    const int wrow0 = bx << 6;
    const int srr = tid >> 2;
    const int skq = (tid & 3) << 3;

    const u16* xph = Xhi + (row0 + srr) * ldx + skq;
    const u16* xpl = Xlo + (row0 + srr) * ldx + skq;
    const u16* wph = Whi + (wrow0 + srr) * K + skq;
    const u16* wpl = Wlo + (wrow0 + srr) * K + skq;

    f32x4 acc[4] = {};
    const int niter = K >> 5;

    // prologue: stage iter 0 into buffer 0
    *(uint4*)&sh.A[0][0][srr][skq]  = *(const uint4*)(xph);
    *(uint4*)&sh.A[0][1][srr][skq]  = *(const uint4*)(xpl);
    *(uint4*)&sh.Bw[0][0][srr][skq] = *(const uint4*)(wph);
    *(uint4*)&sh.Bw[0][1][srr][skq] = *(const uint4*)(wpl);
    __syncthreads();

    for (int i = 0; i < niter; ++i) {
        const int cur = i & 1, nxt = cur ^ 1;
        uint4 pah, pal, pbh, pbl;
        const bool pf = (i + 1 < niter);
        if (pf) {
            int k = (i + 1) << 5;
            pah = *(const uint4*)(xph + k);
            pal = *(const uint4*)(xpl + k);
            pbh = *(const uint4*)(wph + k);
            pbl = *(const uint4*)(wpl + k);
        }
        bf16x8 ah = *(const bf16x8*)&sh.A[cur][0][(ws << 4) + fr][ko];
        bf16x8 al = *(const bf16x8*)&sh.A[cur][1][(ws << 4) + fr][ko];
        #pragma unroll
        for (int nt = 0; nt < 4; ++nt) {
            bf16x8 bh = *(const bf16x8*)&sh.Bw[cur][0][(nt << 4) + fr][ko];
            bf16x8 bl = *(const bf16x8*)&sh.Bw[cur][1][(nt << 4) + fr][ko];
            acc[nt] = __builtin_amdgcn_mfma_f32_16x16x32_bf16(ah, bh, acc[nt], 0, 0, 0);
            acc[nt] = __builtin_amdgcn_mfma_f32_16x16x32_bf16(ah, bl, acc[nt], 0, 0, 0);
            acc[nt] = __builtin_amdgcn_mfma_f32_16x16x32_bf16(al, bh, acc[nt], 0, 0, 0);
        }
        if (pf) {
            *(uint4*)&sh.A[nxt][0][srr][skq]  = pah;
            *(uint4*)&sh.A[nxt][1][srr][skq]  = pal;
            *(uint4*)&sh.Bw[nxt][0][srr][skq] = pbh;
            *(uint4*)&sh.Bw[nxt][1][srr][skq] = pbl;
        }
        __syncthreads();
    }

    // ---- epilogue: LSTM cell ----
    const int cell = (bx << 4) + fr;
    const int rbase = row0 + (ws << 4) + (quad << 2);
    float bb[4];
    if (biaspk) {
        #pragma unroll
        for (int g = 0; g < 4; ++g) bb[g] = biaspk[(bx << 6) + (g << 4) + fr];
    }
    #pragma unroll
    for (int r = 0; r < 4; ++r) {
        int b = rbase + r;
        float gi = acc[0][r], gf = acc[1][r], gg = acc[2][r], go = acc[3][r];
        if (base) {
            const float* bp = base + b * G4 + (bx << 6) + fr;
            gi += bp[0]; gf += bp[16]; gg += bp[32]; go += bp[48];
        } else {
            gi += bb[0]; gf += bb[1]; gg += bb[2]; go += bb[3];
        }
        float cold = c[(b << 9) + cell];
        float cn = sigm(gf) * cold + sigm(gi) * tanhf(gg);
        c[(b << 9) + cell] = cn;
        float h = sigm(go) * tanhf(cn);
        u16 hh = f2bf(h);
        Xnhi[b * ldxn + hcol0 + cell] = hh;
        Xnlo[b * ldxn + hcol0 + cell] = f2bf(h - bf2f(hh));
        if (hfp) hfp[(b << 9) + cell] = h;
        if (lens && t == lens[b] - 1) tcat[b * TDIM + 8 + cell] = h;
    }

    // ---- encoder: stage x columns (emb + ts) for step t+1 ----
    if (acts && bx == 0 && t < TT - 1) {
        for (int idx = tid; idx < 64 * 65; idx += 256) {
            int r = idx / 65, cc = idx - r * 65;
            int b = row0 + r;
            float v = (cc < 64) ? act_emb[acts[(b << 6) + t + 1] * 64 + cc]
                                : tsv[(b << 6) + t + 1];
            u16 hh = f2bf(v);
            Xnhi[b * ldxn + cc] = hh;
            Xnlo[b * ldxn + cc] = f2bf(v - bf2f(hh));
        }
    }
}

// ---------------------------------------------------------------------------
// Persistent encoder: 64 LSTM steps, one grid barrier per step.
// ---------------------------------------------------------------------------
struct EncArgs {
    const u16 *We_hi, *We_lo;
    const float* bias_e;
    float* c_e;
    u16 *Xe_hi, *Xe_lo;
    float* tcat;
    const int* lens;
    const int* acts;
    const float* tsv;
    const float* act_emb;
    unsigned *cnt, *gen;
};

__global__ __launch_bounds__(256) void enc_persist(EncArgs a) {
    __shared__ GemmShared sh;
    const int bx = blockIdx.x & 31, by = blockIdx.x >> 5;
    for (int t = 0; t < TT; ++t) {
        const u16* xh = a.Xe_hi + (size_t)(t & 1) * B * 608;
        const u16* xl = a.Xe_lo + (size_t)(t & 1) * B * 608;
        u16* xnh = a.Xe_hi + (size_t)((t + 1) & 1) * B * 608;
        u16* xnl = a.Xe_lo + (size_t)((t + 1) & 1) * B * 608;
        gemm_cell_phase(sh, xh, xl, 608, a.We_hi, a.We_lo, 608,
                        nullptr, a.bias_e, a.c_e, xnh, xnl, 608, 65,
                        nullptr, a.tcat, a.lens, t, a.acts, a.tsv, a.act_emb,
                        bx, by);
        gbar(a.cnt, a.gen, 256);
    }
}

// ---------------------------------------------------------------------------
// Persistent decoder: per step 4 phases with grid barriers:
//   A: act-LSTM gemm+cell    B: logits/softmax/argmax/embed feedback
//   C: time-LSTM gemm+cell   D: fused ts1+ts2 head + tsc feedback
// ---------------------------------------------------------------------------
struct DecArgs {
    const u16 *Wa_hi, *Wa_lo, *Wt_hi, *Wt_lo;
    const float *base_a, *base_t;
    float *c_a, *c_t, *htb;
    u16 *Xa_hi, *Xa_lo, *Xt_hi, *Xt_lo;
    const float *WtT, *e2b, *act_emb;
    const float *W1T, *b1, *w2, *b2;
    float *out_acts, *out_ts;
    unsigned *cnt, *gen;
};

__global__ __launch_bounds__(256) void dec_persist(DecArgs a) {
    __shared__ GemmShared sh;
    __shared__ float hs[4][512];
    __shared__ float hs2[2][512];
    __shared__ float redA[4], redB[4];
    const int bx = blockIdx.x & 31, by = blockIdx.x >> 5;

    for (int t = 0; t < TT; ++t) {
        u16* xah  = a.Xa_hi + (size_t)(t & 1) * B * 576;
        u16* xal  = a.Xa_lo + (size_t)(t & 1) * B * 576;
        u16* xanh = a.Xa_hi + (size_t)((t + 1) & 1) * B * 576;
        u16* xanl = a.Xa_lo + (size_t)((t + 1) & 1) * B * 576;
        u16* xth  = a.Xt_hi + (size_t)(t & 1) * B * 608;
        u16* xtl  = a.Xt_lo + (size_t)(t & 1) * B * 608;
        u16* xtnh = a.Xt_hi + (size_t)((t + 1) & 1) * B * 608;
        u16* xtnl = a.Xt_lo + (size_t)((t + 1) & 1) * B * 608;

        // ---- Phase A: act-LSTM ----
        gemm_cell_phase(sh, xah, xal, 576, a.Wa_hi, a.Wa_lo, 576,
                        a.base_a, nullptr, a.c_a, xanh, xanl, 576, 64,
                        nullptr, nullptr, nullptr, t, nullptr, nullptr, nullptr,
                        bx, by);
        gbar(a.cnt, a.gen, 256);

        // ---- Phase B: act head (blocks 0..127, one row per wave) ----
        if (blockIdx.x < 128) {
            const int w = threadIdx.x >> 6;
            const int aa = threadIdx.x & 63;
            const int r = (blockIdx.x << 2) + w;
            for (int k = aa; k < 512; k += 64)
                hs[w][k] = bf2f(xanh[r * 576 + 64 + k]) + bf2f(xanl[r * 576 + 64 + k]);
            float l = a.e2b[aa];
            #pragma unroll 8
            for (int k = 0; k < 512; ++k) l = fmaf(hs[w][k], a.WtT[(k << 6) + aa], l);
            float m = l;
            #pragma unroll
            for (int off = 32; off; off >>= 1) m = fmaxf(m, __shfl_xor(m, off));
            float e = expf(l - m), s = e;
            #pragma unroll
            for (int off = 32; off; off >>= 1) s += __shfl_xor(s, off);
            a.out_acts[(((size_t)r << 6) + t) * 64 + aa] = e / s;
            unsigned long long mask = __ballot(l == m);
            int amax = __ffsll(mask) - 1;   // first max index (jnp.argmax)
            float av = a.act_emb[(amax << 6) + aa];
            u16 hh = f2bf(av), hl = f2bf(av - bf2f(hh));
            xanh[r * 576 + aa] = hh; xanl[r * 576 + aa] = hl;  // ae (next step)
            xth[r * 608 + aa]  = hh; xtl[r * 608 + aa]  = hl;  // ae2 (this step)
        }
        gbar(a.cnt, a.gen, 256);

        // ---- Phase C: time-LSTM ----
        gemm_cell_phase(sh, xth, xtl, 608, a.Wt_hi, a.Wt_lo, 608,
                        a.base_t, nullptr, a.c_t, xtnh, xtnl, 608, 65,
                        a.htb, nullptr, nullptr, t, nullptr, nullptr, nullptr,
                        bx, by);
        gbar(a.cnt, a.gen, 256);

        // ---- Phase D: fused ts head (2 rows per block) ----
        {
            const int r0 = blockIdx.x << 1;
            for (int i = threadIdx.x; i < 1024; i += 256)
                hs2[i >> 9][i & 511] = a.htb[(((size_t)r0 + (i >> 9)) << 9) + (i & 511)];
            __syncthreads();
            const int j = threadIdx.x;
            float a0 = 0.f, a1 = 0.f;
            for (int k = 0; k < 512; ++k) {
                float wv = a.W1T[(k << 8) + j];
                a0 = fmaf(hs2[0][k], wv, a0);
                a1 = fmaf(hs2[1][k], wv, a1);
            }
            float b1v = a.b1[j], w2v = a.w2[j];
            a0 = fmaxf(a0 + b1v, 0.f) * w2v;
            a1 = fmaxf(a1 + b1v, 0.f) * w2v;
            #pragma unroll
            for (int off = 32; off; off >>= 1) {
                a0 += __shfl_xor(a0, off);
                a1 += __shfl_xor(a1, off);
            }
            const int wv_ = threadIdx.x >> 6;
            if ((threadIdx.x & 63) == 0) { redA[wv_] = a0; redB[wv_] = a1; }
            __syncthreads();
            if (threadIdx.x == 0) {
                float s0 = redA[0] + redA[1] + redA[2] + redA[3] + a.b2[0];
                float s1 = redB[0] + redB[1] + redB[2] + redB[3] + a.b2[0];
                a.out_ts[((size_t)r0 << 6) + t] = s0;
                a.out_ts[(((size_t)r0 + 1) << 6) + t] = s1;
                u16 h0 = f2bf(s0), h1 = f2bf(s1);
                xtnh[r0 * 608 + 64] = h0;
                xtnl[r0 * 608 + 64] = f2bf(s0 - bf2f(h0));
                xtnh[(r0 + 1) * 608 + 64] = h1;
                xtnl[(r0 + 1) * 608 + 64] = f2bf(s1 - bf2f(h1));
            }
        }
        gbar(a.cnt, a.gen, 256);
    }
}

// ---------------------------------------------------------------------------
// fp32 GEMM for latent / decoder-prep: C[M,N] = A[M,K] @ W[N,K]^T (+bias)(relu).
// permW: index W rows through gate-grouped permutation.
// ---------------------------------------------------------------------------
__global__ __launch_bounds__(256) void gemm_tn(
    const float* __restrict__ A, int lda,
    const float* __restrict__ W, int ldw,
    int N, int K,
    const float* __restrict__ bias,
    float* __restrict__ C, int ldc,
    int relu, int permW)
{
    __shared__ __align__(16) float As[32][68];
    __shared__ __align__(16) float Ws[32][68];
    const int tid = threadIdx.x;
    const int tx = tid & 15, ty = tid >> 4;
    const int row0 = blockIdx.y << 6;
    const int col0 = blockIdx.x << 6;

    float acc[4][4] = {};

    for (int k0 = 0; k0 < K; k0 += 32) {
        #pragma unroll
        for (int s = 0; s < 2; ++s) {
            int f = tid + (s << 8);
            int rr = f >> 3;
            int kq = (f & 7) << 2;
            int k = k0 + kq;
            float4 v = make_float4(0.f, 0.f, 0.f, 0.f);
            const float* ap = A + (size_t)(row0 + rr) * (size_t)lda;
            if (k + 3 < K) v = *(const float4*)(ap + k);
            else {
                if (k + 0 < K) v.x = ap[k + 0];
                if (k + 1 < K) v.y = ap[k + 1];
                if (k + 2 < K) v.z = ap[k + 2];
            }
            As[kq + 0][rr] = v.x; As[kq + 1][rr] = v.y;
            As[kq + 2][rr] = v.z; As[kq + 3][rr] = v.w;
        }
        #pragma unroll
        for (int s = 0; s < 2; ++s) {
            int f = tid + (s << 8);
            int rr = f >> 3;
            int kq = (f & 7) << 2;
            int k = k0 + kq;
            int n = col0 + rr;
            float4 v = make_float4(0.f, 0.f, 0.f, 0.f);
            if (n < N) {
                int nsrc = n;
                if (permW) {
                    int g = (n & 63) >> 4;
                    int cell = ((n >> 6) << 4) + (n & 15);
                    nsrc = (g << 9) + cell;
                }
                const float* wp = W + (size_t)nsrc * (size_t)ldw;
                if (k + 3 < K) v = *(const float4*)(wp + k);
                else {
                    if (k + 0 < K) v.x = wp[k + 0];
                    if (k + 1 < K) v.y = wp[k + 1];
                    if (k + 2 < K) v.z = wp[k + 2];
                }
            }
            Ws[kq + 0][rr] = v.x; Ws[kq + 1][rr] = v.y;
            Ws[kq + 2][rr] = v.z; Ws[kq + 3][rr] = v.w;
        }
        __syncthreads();
        #pragma unroll
        for (int k = 0; k < 32; ++k) {
            float4 av = *(const float4*)&As[k][ty << 2];
            float4 bv = *(const float4*)&Ws[k][tx << 2];
            acc[0][0] = fmaf(av.x, bv.x, acc[0][0]);
            acc[0][1] = fmaf(av.x, bv.y, acc[0][1]);
            acc[0][2] = fmaf(av.x, bv.z, acc[0][2]);
            acc[0][3] = fmaf(av.x, bv.w, acc[0][3]);
            acc[1][0] = fmaf(av.y, bv.x, acc[1][0]);
            acc[1][1] = fmaf(av.y, bv.y, acc[1][1]);
            acc[1][2] = fmaf(av.y, bv.z, acc[1][2]);
            acc[1][3] = fmaf(av.y, bv.w, acc[1][3]);
            acc[2][0] = fmaf(av.z, bv.x, acc[2][0]);
            acc[2][1] = fmaf(av.z, bv.y, acc[2][1]);
            acc[2][2] = fmaf(av.z, bv.z, acc[2][2]);
            acc[2][3] = fmaf(av.z, bv.w, acc[2][3]);
            acc[3][0] = fmaf(av.w, bv.x, acc[3][0]);
            acc[3][1] = fmaf(av.w, bv.y, acc[3][1]);
            acc[3][2] = fmaf(av.w, bv.z, acc[3][2]);
            acc[3][3] = fmaf(av.w, bv.w, acc[3][3]);
        }
        __syncthreads();
    }

    #pragma unroll
    for (int i = 0; i < 4; ++i) {
        int rr = row0 + (ty << 2) + i;
        float* cp = C + (size_t)rr * (size_t)ldc;
        #pragma unroll
        for (int j = 0; j < 4; ++j) {
            int cc = col0 + (tx << 2) + j;
            if (cc < N) {
                float v = acc[i][j];
                if (bias) v += bias[cc];
                if (relu) v = fmaxf(v, 0.f);
                cp[cc] = v;
            }
        }
    }
}

// ---------------------------------------------------------------------------
// Weight packing (gate-grouped, hi/lo bf16, zero-padded K).
// ---------------------------------------------------------------------------
__device__ __forceinline__ int perm_src(int np) {
    int g = (np & 63) >> 4;
    int cell = ((np >> 6) << 4) + (np & 15);
    return (g << 9) + cell;
}
__global__ void pack_we(u16* __restrict__ hi, u16* __restrict__ lo,
                        const float* __restrict__ wih, const float* __restrict__ whh) {
    int idx = blockIdx.x * 256 + threadIdx.x;
    if (idx >= G4 * 608) return;
    int np = idx / 608, k = idx - np * 608;
    int n = perm_src(np);
    float v = 0.f;
    if (k < 65) v = wih[n * 65 + k];
    else if (k < 577) v = whh[(n << 9) + k - 65];
    u16 h = f2bf(v); hi[idx] = h; lo[idx] = f2bf(v - bf2f(h));
}
__global__ void pack_wa(u16* __restrict__ hi, u16* __restrict__ lo,
                        const float* __restrict__ wih, const float* __restrict__ whh) {
    int idx = blockIdx.x * 256 + threadIdx.x;
    if (idx >= G4 * 576) return;
    int np = idx / 576, k = idx - np * 576;
    int n = perm_src(np);
    float v = (k < 64) ? wih[n * 584 + 520 + k] : whh[(n << 9) + k - 64];
    u16 h = f2bf(v); hi[idx] = h; lo[idx] = f2bf(v - bf2f(h));
}
__global__ void pack_wt(u16* __restrict__ hi, u16* __restrict__ lo,
                        const float* __restrict__ wih, const float* __restrict__ whh) {
    int idx = blockIdx.x * 256 + threadIdx.x;
    if (idx >= G4 * 608) return;
    int np = idx / 608, k = idx - np * 608;
    int n = perm_src(np);
    float v = 0.f;
    if (k < 64) v = wih[n * 585 + 520 + k];
    else if (k == 64) v = wih[n * 585 + 584];
    else if (k < 577) v = whh[(n << 9) + k - 65];
    u16 h = f2bf(v); hi[idx] = h; lo[idx] = f2bf(v - bf2f(h));
}

// biases, WtT transpose, W1T transpose, barrier zero. grid 512x256.
__global__ void prep_misc(float* __restrict__ be, float* __restrict__ ba, float* __restrict__ bt,
                          float* __restrict__ wt, float* __restrict__ w1t,
                          unsigned* __restrict__ bar,
                          const float* __restrict__ ebih, const float* __restrict__ ebhh,
                          const float* __restrict__ abih, const float* __restrict__ abhh,
                          const float* __restrict__ tbih, const float* __restrict__ tbhh,
                          const float* __restrict__ e2w, const float* __restrict__ ts1W) {
    int idx = blockIdx.x * 256 + threadIdx.x;
    if (idx < 2) bar[idx] = 0u;
    if (idx < G4) {
        int n = perm_src(idx);
        be[idx] = ebih[n] + ebhh[n];
        ba[idx] = abih[n] + abhh[n];
        bt[idx] = tbih[n] + tbhh[n];
    }
    if (idx < 512 * 64) {  // WtT[k][a] = e2act_W[a][k]
        int k = idx >> 6, aa = idx & 63;
        wt[idx] = e2w[(aa << 9) + k];
    }
    if (idx < 512 * 256) { // W1T[k][j] = ts1_W[j][k]
        int k = idx >> 8, j = idx & 255;
        w1t[idx] = ts1W[j * 512 + k];
    }
}

__global__ void attr_enc(float* __restrict__ tcat, const int* __restrict__ attr_cat,
                         const float* __restrict__ attr_num, const float* __restrict__ attr_emb,
                         const float* __restrict__ a2aW, const float* __restrict__ a2ab) {
    int idx = blockIdx.x * 256 + threadIdx.x;
    if (idx >= B * 8) return;
    int b = idx >> 3, o = idx & 7;
    const float* wr = a2aW + o * 17;
    const float* em = attr_emb + attr_cat[b] * 16;
    float s = a2ab[o];
    #pragma unroll
    for (int k = 0; k < 16; ++k) s = fmaf(em[k], wr[k], s);
    s = fmaf(attr_num[b], wr[16], s);
    tcat[b * TDIM + o] = fmaxf(s, 0.f);
}

__global__ __launch_bounds__(256) void enc_init(
    u16* __restrict__ xh, u16* __restrict__ xl, float* __restrict__ ce,
    const int* __restrict__ acts, const float* __restrict__ tsv,
    const float* __restrict__ act_emb, int* __restrict__ lens) {
    int b = blockIdx.x, tid = threadIdx.x;
    for (int j = tid; j < 608; j += 256) {
        float v = 0.f;
        if (j < 64) v = act_emb[acts[b << 6] * 64 + j];
        else if (j == 64) v = tsv[b << 6];
        u16 hh = f2bf(v);
        xh[b * 608 + j] = hh; xl[b * 608 + j] = f2bf(v - bf2f(hh));
        if (j >= 577) { xh[512 * 608 + b * 608 + j] = 0; xl[512 * 608 + b * 608 + j] = 0; }
    }
    for (int j = tid; j < CF; j += 256) ce[(b << 9) + j] = 0.f;
    if (tid < 64) {
        int v = acts[(b << 6) + tid];
        int m = v;
        #pragma unroll
        for (int off = 32; off; off >>= 1) m = max(m, __shfl_xor(m, off));
        unsigned long long mask = __ballot(v == m);
        if (tid == 0) lens[b] = __ffsll(mask) - 1;
    }
}

__global__ void z_kernel(const float* __restrict__ m, const float* __restrict__ v,
                         const float* __restrict__ e, float* __restrict__ z) {
    int i = blockIdx.x * 256 + threadIdx.x;
    if (i < B * ZD) z[i] = fmaf(v[i], e[i], m[i]);
}

__global__ __launch_bounds__(64) void attr_heads(
    const float* __restrict__ hid1, const float* __restrict__ hid2,
    const float* __restrict__ tc2W, const float* __restrict__ tc2b,
    const float* __restrict__ tn2W, const float* __restrict__ tn2b,
    float* __restrict__ out_cat, float* __restrict__ out_num) {
    __shared__ __align__(16) float h1[260], h2[260], sl[10];
    int b = blockIdx.x, tid = threadIdx.x;
    for (int k = tid; k < 260; k += 64) {
        h1[k] = hid1[b * 260 + k];
        h2[k] = hid2[b * 260 + k];
    }
    __syncthreads();
    if (tid < 10) {
        float l = tc2b[tid];
        const float* wr = tc2W + tid * 260;
        for (int k = 0; k < 260; ++k) l = fmaf(h1[k], wr[k], l);
        sl[tid] = l;
    }
    __syncthreads();
    if (tid < 10) {
        float m = sl[0];
        for (int i = 1; i < 10; ++i) m = fmaxf(m, sl[i]);
        float ssum = 0.f;
        for (int i = 0; i < 10; ++i) ssum += expf(sl[i] - m);
        out_cat[b * 10 + tid] = expf(sl[tid] - m) / ssum;
    }
    float p = 0.f;
    for (int k = tid; k < 260; k += 64) p = fmaf(h2[k], tn2W[k], p);
    #pragma unroll
    for (int off = 32; off; off >>= 1) p += __shfl_xor(p, off);
    if (tid == 0) out_num[b] = 1.f / (1.f + expf(-(p + tn2b[0])));
}

__global__ __launch_bounds__(256) void dec_init(
    u16* __restrict__ xah, u16* __restrict__ xal,
    u16* __restrict__ xth, u16* __restrict__ xtl,
    float* __restrict__ ca, float* __restrict__ ct,
    const float* __restrict__ act_emb) {
    int b = blockIdx.x, tid = threadIdx.x;
    for (int j = tid; j < 576; j += 256) {
        float v = (j < 64) ? act_emb[63 * 64 + j] : 0.f;
        u16 hh = f2bf(v);
        xah[b * 576 + j] = hh; xal[b * 576 + j] = f2bf(v - bf2f(hh));
    }
    for (int j = tid; j < 608; j += 256) {
        if (j >= 64) { xth[b * 608 + j] = 0; xtl[b * 608 + j] = 0; }
        if (j >= 577) { xth[512 * 608 + b * 608 + j] = 0; xtl[512 * 608 + b * 608 + j] = 0; }
    }
    for (int j = tid; j < CF; j += 256) { ca[(b << 9) + j] = 0.f; ct[(b << 9) + j] = 0.f; }
}

// ---------------------------------------------------------------------------
extern "C" void kernel_launch(void* const* d_in, const int* in_sizes, int n_in,
                              void* d_out, int out_size, void* d_ws, size_t ws_size,
                              hipStream_t stream) {
    const int*   attr_cat = (const int*)  d_in[0];
    const float* attr_num = (const float*)d_in[1];
    const int*   acts     = (const int*)  d_in[2];
    const float* tsv      = (const float*)d_in[3];
    const float* eps      = (const float*)d_in[4];
    const float* attr_emb = (const float*)d_in[5];
    const float* a2a_W    = (const float*)d_in[6];
    const float* a2a_b    = (const float*)d_in[7];
    const float* act_emb  = (const float*)d_in[8];
    const float* eWih     = (const float*)d_in[9];
    const float* eWhh     = (const float*)d_in[10];
    const float* ebih     = (const float*)d_in[11];
    const float* ebhh     = (const float*)d_in[12];
    const float* mean_W   = (const float*)d_in[13];
    const float* mean_b   = (const float*)d_in[14];
    const float* var_W    = (const float*)d_in[15];
    const float* var_b    = (const float*)d_in[16];
    const float* z2t_W    = (const float*)d_in[17];
    const float* z2t_b    = (const float*)d_in[18];
    const float* tc1_W    = (const float*)d_in[19];
    const float* tc1_b    = (const float*)d_in[20];
    const float* tc2_W    = (const float*)d_in[21];
    const float* tc2_b    = (const float*)d_in[22];
    const float* tn1_W    = (const float*)d_in[23];
    const float* tn1_b    = (const float*)d_in[24];
    const float* tn2_W    = (const float*)d_in[25];
    const float* tn2_b    = (const float*)d_in[26];
    const float* aWih     = (const float*)d_in[27];
    const float* aWhh     = (const float*)d_in[28];
    const float* abih     = (const float*)d_in[29];
    const float* abhh     = (const float*)d_in[30];
    const float* tWih     = (const float*)d_in[31];
    const float* tWhh     = (const float*)d_in[32];
    const float* tbih     = (const float*)d_in[33];
    const float* tbhh     = (const float*)d_in[34];
    const float* e2act_W  = (const float*)d_in[35];
    const float* e2act_b  = (const float*)d_in[36];
    const float* ts1_W    = (const float*)d_in[37];
    const float* ts1_b    = (const float*)d_in[38];
    const float* ts2_W    = (const float*)d_in[39];
    const float* ts2_b    = (const float*)d_in[40];

    float* out = (float*)d_out;
    float* out_cat  = out;
    float* out_num  = out + 5120;
    float* out_acts = out + 5632;
    float* out_ts   = out + 2102784;
    float* outm     = out + 2135552;
    float* outv     = out + 2201088;

    char* w = (char*)d_ws;
    auto alloc = [&](size_t bytes) { char* p = w; w += (bytes + 255) & ~(size_t)255; return p; };
    // --- persistent region ---
    u16*   Wt_hi  = (u16*)alloc((size_t)G4 * 608 * 2);
    u16*   Wt_lo  = (u16*)alloc((size_t)G4 * 608 * 2);
    float* WtT    = (float*)alloc(512 * 64 * 4);
    float* W1T    = (float*)alloc(512 * 256 * 4);
    float* bias_e = (float*)alloc(G4 * 4);
    float* bias_a = (float*)alloc(G4 * 4);
    float* bias_t = (float*)alloc(G4 * 4);
    float* base_a = (float*)alloc((size_t)B * G4 * 4);
    float* base_t = (float*)alloc((size_t)B * G4 * 4);
    u16*   Xa_hi  = (u16*)alloc((size_t)2 * B * 576 * 2);
    u16*   Xa_lo  = (u16*)alloc((size_t)2 * B * 576 * 2);
    u16*   Xt_hi  = (u16*)alloc((size_t)2 * B * 608 * 2);
    u16*   Xt_lo  = (u16*)alloc((size_t)2 * B * 608 * 2);
    float* c_a    = (float*)alloc((size_t)B * CF * 4);
    float* c_t    = (float*)alloc((size_t)B * CF * 4);
    float* htb    = (float*)alloc((size_t)B * CF * 4);
    float* tcat   = (float*)alloc((size_t)B * TDIM * 4);
    float* t_rec  = (float*)alloc((size_t)B * TDIM * 4);
    float* zbuf   = (float*)alloc((size_t)B * ZD * 4);
    float* hid1   = (float*)alloc((size_t)B * 260 * 4);
    float* hid2   = (float*)alloc((size_t)B * 260 * 4);
    int*   lens   = (int*)alloc(512 * 4);
    unsigned* bar = (unsigned*)alloc(2 * 4);
    // --- phase overlay: encoder {We,Xe,c_e} / decoder {Wa} ---
    char* phase = w;
    u16*   We_hi  = (u16*)(phase);
    u16*   We_lo  = (u16*)(phase + (size_t)G4 * 608 * 2);
    u16*   Xe_hi  = (u16*)(phase + (size_t)2 * G4 * 608 * 2);
    u16*   Xe_lo  = (u16*)(phase + (size_t)2 * G4 * 608 * 2 + (size_t)2 * B * 608 * 2);
    float* c_e    = (float*)(phase + (size_t)2 * G4 * 608 * 2 + (size_t)4 * B * 608 * 2);
    u16*   Wa_hi  = (u16*)(phase);
    u16*   Wa_lo  = (u16*)(phase + (size_t)G4 * 576 * 2);
    (void)ws_size; (void)in_sizes; (void)n_in; (void)out_size;

    // ---- prep ----
    pack_we<<<(G4 * 608 + 255) / 256, 256, 0, stream>>>(We_hi, We_lo, eWih, eWhh);
    pack_wt<<<(G4 * 608 + 255) / 256, 256, 0, stream>>>(Wt_hi, Wt_lo, tWih, tWhh);
    prep_misc<<<512, 256, 0, stream>>>(bias_e, bias_a, bias_t, WtT, W1T, bar,
                                       ebih, ebhh, abih, abhh, tbih, tbhh, e2act_W, ts1_W);
    attr_enc<<<(B * 8 + 255) / 256, 256, 0, stream>>>(tcat, attr_cat, attr_num, attr_emb, a2a_W, a2a_b);
    enc_init<<<B, 256, 0, stream>>>(Xe_hi, Xe_lo, c_e, acts, tsv, act_emb, lens);

    // ---- encoder (persistent cooperative) ----
    EncArgs ea;
    ea.We_hi = We_hi; ea.We_lo = We_lo; ea.bias_e = bias_e; ea.c_e = c_e;
    ea.Xe_hi = Xe_hi; ea.Xe_lo = Xe_lo; ea.tcat = tcat; ea.lens = lens;
    ea.acts = acts; ea.tsv = tsv; ea.act_emb = act_emb;
    ea.cnt = bar; ea.gen = bar + 1;
    {
        void* args[] = { &ea };
        hipLaunchCooperativeKernel((const void*)enc_persist, dim3(256), dim3(256),
                                   args, 0, stream);
    }

    // ---- latent ----
    gemm_tn<<<dim3(2, 8, 1), 256, 0, stream>>>(tcat, TDIM, mean_W, TDIM, ZD, TDIM,
                                               mean_b, outm, ZD, 0, 0);
    gemm_tn<<<dim3(2, 8, 1), 256, 0, stream>>>(tcat, TDIM, var_W, TDIM, ZD, TDIM,
                                               var_b, outv, ZD, 0, 0);
    z_kernel<<<(B * ZD + 255) / 256, 256, 0, stream>>>(outm, outv, eps, zbuf);
    gemm_tn<<<dim3(9, 8, 1), 256, 0, stream>>>(zbuf, ZD, z2t_W, ZD, TDIM, ZD,
                                               z2t_b, t_rec, TDIM, 1, 0);
    gemm_tn<<<dim3(5, 8, 1), 256, 0, stream>>>(t_rec, TDIM, tc1_W, TDIM, 260, TDIM,
                                               tc1_b, hid1, 260, 1, 0);
    gemm_tn<<<dim3(5, 8, 1), 256, 0, stream>>>(t_rec, TDIM, tn1_W, TDIM, 260, TDIM,
                                               tn1_b, hid2, 260, 1, 0);
    attr_heads<<<B, 64, 0, stream>>>(hid1, hid2, tc2_W, tc2_b, tn2_W, tn2_b, out_cat, out_num);

    // ---- decoder prep (Wa overlays We region after encoder done) ----
    pack_wa<<<(G4 * 576 + 255) / 256, 256, 0, stream>>>(Wa_hi, Wa_lo, aWih, aWhh);
    gemm_tn<<<dim3(32, 8, 1), 256, 0, stream>>>(t_rec, TDIM, aWih, 584, G4, TDIM,
                                                bias_a, base_a, G4, 0, 1);
    gemm_tn<<<dim3(32, 8, 1), 256, 0, stream>>>(t_rec, TDIM, tWih, 585, G4, TDIM,
                                                bias_t, base_t, G4, 0, 1);
    dec_init<<<B, 256, 0, stream>>>(Xa_hi, Xa_lo, Xt_hi, Xt_lo, c_a, c_t, act_emb);

    // ---- decoder (persistent cooperative) ----
    DecArgs da;
    da.Wa_hi = Wa_hi; da.Wa_lo = Wa_lo; da.Wt_hi = Wt_hi; da.Wt_lo = Wt_lo;
    da.base_a = base_a; da.base_t = base_t;
    da.c_a = c_a; da.c_t = c_t; da.htb = htb;
    da.Xa_hi = Xa_hi; da.Xa_lo = Xa_lo; da.Xt_hi = Xt_hi; da.Xt_lo = Xt_lo;
    da.WtT = WtT; da.e2b = e2act_b; da.act_emb = act_emb;
    da.W1T = W1T; da.b1 = ts1_b; da.w2 = ts2_W; da.b2 = ts2_b;
    da.out_acts = out_acts; da.out_ts = out_ts;
    da.cnt = bar; da.gen = bar + 1;
    {
        void* args[] = { &da };
        hipLaunchCooperativeKernel((const void*)dec_persist, dim3(256), dim3(256),
                                   args, 0, stream);
    }
}

// Round 5
// 6164.491 us; speedup vs baseline: 3.1694x; 3.1694x over previous
//
#include <hip/hip_runtime.h>
#include <math.h>

// ---------------------------------------------------------------------------
// VAE_14482629722138 — round 5: multi-launch, MFMA everywhere, 2 launches per
// decoder step (heads computed block-locally), consolidated prep/latent.
// B=512, T=64, CF=512, ZD=128, TDIM=520.
// ---------------------------------------------------------------------------

#define B 512
#define TT 64
#define CF 512
#define G4 2048
#define ZD 128
#define TDIM 520

typedef unsigned short u16;
typedef short bf16x8 __attribute__((ext_vector_type(8)));
typedef float f32x4 __attribute__((ext_vector_type(4)));

__device__ __forceinline__ float sigm(float x) { return 1.f / (1.f + expf(-x)); }
__device__ __forceinline__ u16 f2bf(float f) {
    unsigned u = __float_as_uint(f);
    u += 0x7fffu + ((u >> 16) & 1u);
    return (u16)(u >> 16);
}
__device__ __forceinline__ float bf2f(u16 s) { return __uint_as_float(((unsigned)s) << 16); }

struct __align__(16) GemmShared {
    u16 A[2][2][64][40];   // [dbuf][hi/lo][row][k(+pad)]
    u16 Bw[2][2][64][40];
};

// ---------------------------------------------------------------------------
// 64x64 MFMA tile, K multiple of 32, A rows: caller-offset base (64 rows,
// stride lda), B rows: dense stride K. TERMS=3: (ah,bh)+(ah,bl)+(al,bh);
// TERMS=2: (ah,bh)+(al,bh) (B hi only). Double-buffered LDS.
// acc[nt][r]: row = ws*16+quad*4+r, col = nt*16+fr.
// ---------------------------------------------------------------------------
template<int TERMS>
__device__ __forceinline__ void gemm64(
    GemmShared& sh,
    const u16* __restrict__ Ah, const u16* __restrict__ Al, int lda,
    const u16* __restrict__ Bh, const u16* __restrict__ Bl, int K,
    f32x4 acc[4])
{
    const int tid = threadIdx.x;
    const int lane = tid & 63, ws = tid >> 6;
    const int fr = lane & 15, quad = lane >> 4, ko = quad << 3;
    const int srr = tid >> 2, skq = (tid & 3) << 3;

    const u16* xph = Ah + srr * lda + skq;
    const u16* xpl = Al + srr * lda + skq;
    const u16* wph = Bh + srr * K + skq;
    const u16* wpl = (TERMS == 3) ? (Bl + srr * K + skq) : (const u16*)0;

    const int niter = K >> 5;
    *(uint4*)&sh.A[0][0][srr][skq]  = *(const uint4*)(xph);
    *(uint4*)&sh.A[0][1][srr][skq]  = *(const uint4*)(xpl);
    *(uint4*)&sh.Bw[0][0][srr][skq] = *(const uint4*)(wph);
    if (TERMS == 3) *(uint4*)&sh.Bw[0][1][srr][skq] = *(const uint4*)(wpl);
    __syncthreads();

    for (int i = 0; i < niter; ++i) {
        const int cur = i & 1, nxt = cur ^ 1;
        uint4 pah, pal, pbh, pbl;
        const bool pf = (i + 1 < niter);
        if (pf) {
            int k = (i + 1) << 5;
            pah = *(const uint4*)(xph + k);
            pal = *(const uint4*)(xpl + k);
            pbh = *(const uint4*)(wph + k);
            if (TERMS == 3) pbl = *(const uint4*)(wpl + k);
        }
        bf16x8 ah = *(const bf16x8*)&sh.A[cur][0][(ws << 4) + fr][ko];
        bf16x8 al = *(const bf16x8*)&sh.A[cur][1][(ws << 4) + fr][ko];
        #pragma unroll
        for (int nt = 0; nt < 4; ++nt) {
            bf16x8 bh = *(const bf16x8*)&sh.Bw[cur][0][(nt << 4) + fr][ko];
            acc[nt] = __builtin_amdgcn_mfma_f32_16x16x32_bf16(ah, bh, acc[nt], 0, 0, 0);
            if (TERMS == 3) {
                bf16x8 bl = *(const bf16x8*)&sh.Bw[cur][1][(nt << 4) + fr][ko];
                acc[nt] = __builtin_amdgcn_mfma_f32_16x16x32_bf16(ah, bl, acc[nt], 0, 0, 0);
            }
            acc[nt] = __builtin_amdgcn_mfma_f32_16x16x32_bf16(al, bh, acc[nt], 0, 0, 0);
        }
        if (pf) {
            *(uint4*)&sh.A[nxt][0][srr][skq]  = pah;
            *(uint4*)&sh.A[nxt][1][srr][skq]  = pal;
            *(uint4*)&sh.Bw[nxt][0][srr][skq] = pbh;
            if (TERMS == 3) *(uint4*)&sh.Bw[nxt][1][srr][skq] = pbl;
        }
        __syncthreads();
    }
}

// ts-head partial: acc over ncg strips of W1 (hi-only bf16, 2-term) -> s[4].
__device__ __forceinline__ void ts_head_body(
    GemmShared& sh, const u16* __restrict__ xth, const u16* __restrict__ xtl,
    const u16* __restrict__ W1h, const float* __restrict__ b1,
    const float* __restrict__ w2, float s[4])
{
    const int lane = threadIdx.x & 63;
    const int fr = lane & 15;
    s[0] = s[1] = s[2] = s[3] = 0.f;
    for (int ncg = 0; ncg < 4; ++ncg) {
        f32x4 ac[4] = {};
        gemm64<2>(sh, xth, xtl, 512, W1h + (size_t)(ncg << 6) * 512, nullptr, 512, ac);
        #pragma unroll
        for (int nt = 0; nt < 4; ++nt) {
            int j = (ncg << 6) + (nt << 4) + fr;
            float b1v = b1[j], w2v = w2[j];
            s[0] += fmaxf(ac[nt][0] + b1v, 0.f) * w2v;
            s[1] += fmaxf(ac[nt][1] + b1v, 0.f) * w2v;
            s[2] += fmaxf(ac[nt][2] + b1v, 0.f) * w2v;
            s[3] += fmaxf(ac[nt][3] + b1v, 0.f) * w2v;
        }
    }
    #pragma unroll
    for (int off = 1; off < 16; off <<= 1) {
        s[0] += __shfl_xor(s[0], off);
        s[1] += __shfl_xor(s[1], off);
        s[2] += __shfl_xor(s[2], off);
        s[3] += __shfl_xor(s[3], off);
    }
}

// ---------------------------------------------------------------------------
// Encoder step: gemm (K=608) + LSTM cell + tcat capture + next-x staging.
// ---------------------------------------------------------------------------
__global__ __launch_bounds__(256) void enc_step(
    const u16* __restrict__ xh, const u16* __restrict__ xl,
    const u16* __restrict__ Weh, const u16* __restrict__ Wel,
    const float* __restrict__ biaspk, float* __restrict__ c,
    u16* __restrict__ xnh, u16* __restrict__ xnl,
    float* __restrict__ tcat, const int* __restrict__ lens,
    const int* __restrict__ acts, const float* __restrict__ tsv,
    const float* __restrict__ act_emb, int t)
{
    __shared__ GemmShared sh;
    const int bx = blockIdx.x, by = blockIdx.y, row0 = by << 6;
    const int tid = threadIdx.x, lane = tid & 63, ws = tid >> 6;
    const int fr = lane & 15, quad = lane >> 4;

    f32x4 acc[4] = {};
    gemm64<3>(sh, xh + (size_t)row0 * 608, xl + (size_t)row0 * 608, 608,
              Weh + (size_t)(bx << 6) * 608, Wel + (size_t)(bx << 6) * 608, 608, acc);

    const int cell = (bx << 4) + fr;
    const int rbase = row0 + (ws << 4) + (quad << 2);
    float bb[4];
    #pragma unroll
    for (int g = 0; g < 4; ++g) bb[g] = biaspk[(bx << 6) + (g << 4) + fr];
    #pragma unroll
    for (int r = 0; r < 4; ++r) {
        int b = rbase + r;
        float gi = acc[0][r] + bb[0], gf = acc[1][r] + bb[1];
        float gg = acc[2][r] + bb[2], go = acc[3][r] + bb[3];
        float cold = c[(b << 9) + cell];
        float cn = sigm(gf) * cold + sigm(gi) * tanhf(gg);
        c[(b << 9) + cell] = cn;
        float h = sigm(go) * tanhf(cn);
        u16 hh = f2bf(h);
        xnh[b * 608 + 65 + cell] = hh;
        xnl[b * 608 + 65 + cell] = f2bf(h - bf2f(hh));
        if (t == lens[b] - 1) tcat[b * TDIM + 8 + cell] = h;
    }
    if (bx == 0 && t < TT - 1) {
        for (int idx = tid; idx < 64 * 65; idx += 256) {
            int r = idx / 65, cc = idx - r * 65;
            int b = row0 + r;
            float v = (cc < 64) ? act_emb[acts[(b << 6) + t + 1] * 64 + cc]
                                : tsv[(b << 6) + t + 1];
            u16 hh = f2bf(v);
            xnh[b * 608 + cc] = hh;
            xnl[b * 608 + cc] = f2bf(v - bf2f(hh));
        }
    }
}

// ---------------------------------------------------------------------------
// Decoder K1: gemm_a (K=576) + cell_a; bx==0: ts-head (tsc for this step,
// out_ts[t-1]).
// ---------------------------------------------------------------------------
__global__ __launch_bounds__(256) void dec_k1(
    const u16* __restrict__ xah, const u16* __restrict__ xal,
    u16* __restrict__ xanh, u16* __restrict__ xanl,
    const u16* __restrict__ Wah, const u16* __restrict__ Wal,
    const float* __restrict__ base_a, float* __restrict__ c_a,
    const u16* __restrict__ xth, const u16* __restrict__ xtl,
    const u16* __restrict__ W1h, const float* __restrict__ b1,
    const float* __restrict__ w2, const float* __restrict__ b2p,
    float* __restrict__ ts_val, float* __restrict__ out_ts, int t)
{
    __shared__ GemmShared sh;
    const int bx = blockIdx.x, by = blockIdx.y, row0 = by << 6;
    const int tid = threadIdx.x, lane = tid & 63, ws = tid >> 6;
    const int fr = lane & 15, quad = lane >> 4;

    f32x4 acc[4] = {};
    gemm64<3>(sh, xah + (size_t)row0 * 576, xal + (size_t)row0 * 576, 576,
              Wah + (size_t)(bx << 6) * 576, Wal + (size_t)(bx << 6) * 576, 576, acc);

    const int cell = (bx << 4) + fr;
    const int rbase = row0 + (ws << 4) + (quad << 2);
    #pragma unroll
    for (int r = 0; r < 4; ++r) {
        int b = rbase + r;
        const float* bp = base_a + (size_t)b * G4 + (bx << 6) + fr;
        float gi = acc[0][r] + bp[0], gf = acc[1][r] + bp[16];
        float gg = acc[2][r] + bp[32], go = acc[3][r] + bp[48];
        float cold = c_a[(b << 9) + cell];
        float cn = sigm(gf) * cold + sigm(gi) * tanhf(gg);
        c_a[(b << 9) + cell] = cn;
        float h = sigm(go) * tanhf(cn);
        u16 hh = f2bf(h);
        xanh[b * 576 + 64 + cell] = hh;
        xanl[b * 576 + 64 + cell] = f2bf(h - bf2f(hh));
    }

    if (bx == 0 && t > 0) {
        float s[4];
        ts_head_body(sh, xth + (size_t)row0 * 512, xtl + (size_t)row0 * 512,
                     W1h, b1, w2, s);
        if (fr == 0) {
            float bb2 = b2p[0];
            int rb = row0 + (ws << 4) + (quad << 2);
            #pragma unroll
            for (int r = 0; r < 4; ++r) {
                float v = s[r] + bb2;
                ts_val[rb + r] = v;
                out_ts[((rb + r) << 6) + t - 1] = v;
            }
        }
    }
}

// ---------------------------------------------------------------------------
// Decoder K2: act-head (MFMA logits + softmax + argmax + embed, block-local)
// then gemm_t (K=608: h global | ae2 LDS | tsc synth) + cell_t.
// ---------------------------------------------------------------------------
__global__ __launch_bounds__(256) void dec_k2(
    u16* __restrict__ xanh, u16* __restrict__ xanl,
    const u16* __restrict__ E2h, const u16* __restrict__ E2l,
    const float* __restrict__ e2b, const float* __restrict__ act_emb,
    float* __restrict__ out_acts,
    const u16* __restrict__ Wth, const u16* __restrict__ Wtl,
    const float* __restrict__ base_t, float* __restrict__ c_t,
    const u16* __restrict__ xth, const u16* __restrict__ xtl,
    u16* __restrict__ xtnh, u16* __restrict__ xtnl,
    const float* __restrict__ ts_val, int t)
{
    __shared__ GemmShared sh;
    __shared__ u16 ae2h[64][64];
    __shared__ u16 ae2l[64][64];
    const int bx = blockIdx.x, by = blockIdx.y, row0 = by << 6;
    const int tid = threadIdx.x, lane = tid & 63, ws = tid >> 6;
    const int fr = lane & 15, quad = lane >> 4;
    const int srr = tid >> 2, skq = (tid & 3) << 3;
    const bool bx0 = (bx == 0);

    // ---- act head ----
    {
        f32x4 acc[4] = {};
        gemm64<3>(sh, xanh + (size_t)row0 * 576 + 64, xanl + (size_t)row0 * 576 + 64, 576,
                  E2h, E2l, 512, acc);
        float e2bv[4];
        #pragma unroll
        for (int nt = 0; nt < 4; ++nt) e2bv[nt] = e2b[(nt << 4) + fr];
        const int rl0 = (ws << 4) + (quad << 2);
        #pragma unroll
        for (int r = 0; r < 4; ++r) {
            float l0 = acc[0][r] + e2bv[0], l1 = acc[1][r] + e2bv[1];
            float l2 = acc[2][r] + e2bv[2], l3 = acc[3][r] + e2bv[3];
            float m = fmaxf(fmaxf(l0, l1), fmaxf(l2, l3));
            #pragma unroll
            for (int off = 1; off < 16; off <<= 1) m = fmaxf(m, __shfl_xor(m, off));
            float e0 = expf(l0 - m), e1 = expf(l1 - m);
            float e2v = expf(l2 - m), e3 = expf(l3 - m);
            float sm = e0 + e1 + e2v + e3;
            #pragma unroll
            for (int off = 1; off < 16; off <<= 1) sm += __shfl_xor(sm, off);
            float bv = l0; int bc = fr;
            if (l1 > bv) { bv = l1; bc = 16 + fr; }
            if (l2 > bv) { bv = l2; bc = 32 + fr; }
            if (l3 > bv) { bv = l3; bc = 48 + fr; }
            #pragma unroll
            for (int off = 1; off < 16; off <<= 1) {
                float ov = __shfl_xor(bv, off);
                int oc = __shfl_xor(bc, off);
                if (ov > bv || (ov == bv && oc < bc)) { bv = ov; bc = oc; }
            }
            int rl = rl0 + r, b = row0 + rl;
            if (bx0) {
                float inv = 1.f / sm;
                float* op = out_acts + (((size_t)(b << 6) + t) << 6);
                op[fr] = e0 * inv; op[16 + fr] = e1 * inv;
                op[32 + fr] = e2v * inv; op[48 + fr] = e3 * inv;
            }
            #pragma unroll
            for (int ci = 0; ci < 4; ++ci) {
                int cc = (fr << 2) + ci;
                float v = act_emb[(bc << 6) + cc];
                u16 hh = f2bf(v), hl = f2bf(v - bf2f(hh));
                ae2h[rl][cc] = hh; ae2l[rl][cc] = hl;
                if (bx0) { xanh[b * 576 + cc] = hh; xanl[b * 576 + cc] = hl; }
            }
        }
    }
    __syncthreads();

    // ---- gemm_t (single-buffer, mixed-source A) ----
    f32x4 acc[4] = {};
    {
        const u16* Xh = xth + (size_t)row0 * 512;
        const u16* Xl = xtl + (size_t)row0 * 512;
        const u16* wph = Wth + (size_t)((bx << 6) + srr) * 608 + skq;
        const u16* wpl = Wtl + (size_t)((bx << 6) + srr) * 608 + skq;
        const float* tsp = (t == 0) ? nullptr : (ts_val + row0);
        const int ko = quad << 3;
        for (int i = 0; i < 19; ++i) {
            int k0 = i << 5;
            uint4 vh, vl;
            if (i < 16) {
                vh = *(const uint4*)(Xh + srr * 512 + k0 + skq);
                vl = *(const uint4*)(Xl + srr * 512 + k0 + skq);
            } else if (i < 18) {
                int co = k0 - 512 + skq;
                vh = *(const uint4*)&ae2h[srr][co];
                vl = *(const uint4*)&ae2l[srr][co];
            } else {
                union U { uint4 q; u16 s[8]; } uh, ul;
                uh.q = make_uint4(0, 0, 0, 0); ul.q = make_uint4(0, 0, 0, 0);
                if (skq == 0) {
                    float ts = tsp ? tsp[srr] : 0.f;
                    u16 hh = f2bf(ts);
                    uh.s[0] = hh; ul.s[0] = f2bf(ts - bf2f(hh));
                }
                vh = uh.q; vl = ul.q;
            }
            uint4 wh = *(const uint4*)(wph + k0);
            uint4 wl = *(const uint4*)(wpl + k0);
            __syncthreads();
            *(uint4*)&sh.A[0][0][srr][skq] = vh;
            *(uint4*)&sh.A[0][1][srr][skq] = vl;
            *(uint4*)&sh.Bw[0][0][srr][skq] = wh;
            *(uint4*)&sh.Bw[0][1][srr][skq] = wl;
            __syncthreads();
            bf16x8 ah = *(const bf16x8*)&sh.A[0][0][(ws << 4) + fr][ko];
            bf16x8 al = *(const bf16x8*)&sh.A[0][1][(ws << 4) + fr][ko];
            #pragma unroll
            for (int nt = 0; nt < 4; ++nt) {
                bf16x8 bh = *(const bf16x8*)&sh.Bw[0][0][(nt << 4) + fr][ko];
                bf16x8 bl = *(const bf16x8*)&sh.Bw[0][1][(nt << 4) + fr][ko];
                acc[nt] = __builtin_amdgcn_mfma_f32_16x16x32_bf16(ah, bh, acc[nt], 0, 0, 0);
                acc[nt] = __builtin_amdgcn_mfma_f32_16x16x32_bf16(ah, bl, acc[nt], 0, 0, 0);
                acc[nt] = __builtin_amdgcn_mfma_f32_16x16x32_bf16(al, bh, acc[nt], 0, 0, 0);
            }
        }
    }
    // ---- cell_t ----
    const int cell = (bx << 4) + fr;
    const int rbase = row0 + (ws << 4) + (quad << 2);
    #pragma unroll
    for (int r = 0; r < 4; ++r) {
        int b = rbase + r;
        const float* bp = base_t + (size_t)b * G4 + (bx << 6) + fr;
        float gi = acc[0][r] + bp[0], gf = acc[1][r] + bp[16];
        float gg = acc[2][r] + bp[32], go = acc[3][r] + bp[48];
        float cold = c_t[(b << 9) + cell];
        float cn = sigm(gf) * cold + sigm(gi) * tanhf(gg);
        c_t[(b << 9) + cell] = cn;
        float h = sigm(go) * tanhf(cn);
        u16 hh = f2bf(h);
        xtnh[(b << 9) + cell] = hh;
        xtnl[(b << 9) + cell] = f2bf(h - bf2f(hh));
    }
}

// Final ts output column (head of h_t(63)). grid (1,8).
__global__ __launch_bounds__(256) void ts_tail(
    const u16* __restrict__ xth, const u16* __restrict__ xtl,
    const u16* __restrict__ W1h, const float* __restrict__ b1,
    const float* __restrict__ w2, const float* __restrict__ b2p,
    float* __restrict__ out_ts)
{
    __shared__ GemmShared sh;
    const int by = blockIdx.y, row0 = by << 6;
    const int lane = threadIdx.x & 63, ws = threadIdx.x >> 6;
    const int fr = lane & 15, quad = lane >> 4;
    float s[4];
    ts_head_body(sh, xth + (size_t)row0 * 512, xtl + (size_t)row0 * 512, W1h, b1, w2, s);
    if (fr == 0) {
        float bb2 = b2p[0];
        int rb = row0 + (ws << 4) + (quad << 2);
        #pragma unroll
        for (int r = 0; r < 4; ++r) out_ts[((rb + r) << 6) + 63] = s[r] + bb2;
    }
}

// ---------------------------------------------------------------------------
// fp32 GEMM: C[M,N] = A[M,K] @ W[N,K]^T (+bias)(relu). blockIdx.z==1 selects
// the second (W,bias,C) set. Am!=null => A = Am + Av*Ae elementwise (z-mode).
// permW: gate-grouped W row permutation.
// ---------------------------------------------------------------------------
__device__ __forceinline__ int perm_src(int np) {
    int g = (np & 63) >> 4;
    int cell = ((np >> 6) << 4) + (np & 15);
    return (g << 9) + cell;
}

__global__ __launch_bounds__(256) void gemm_tn(
    const float* __restrict__ A, const float* __restrict__ Am,
    const float* __restrict__ Av, const float* __restrict__ Ae, int lda,
    const float* __restrict__ W1p, int ldw1,
    const float* __restrict__ W2p, int ldw2,
    int N, int K,
    const float* __restrict__ b1p, const float* __restrict__ b2p,
    float* __restrict__ C1, float* __restrict__ C2, int ldc,
    int relu, int permW)
{
    const float* W = W1p; int ldw = ldw1;
    const float* bias = b1p; float* C = C1;
    if (blockIdx.z == 1) { W = W2p; ldw = ldw2; bias = b2p; C = C2; }

    __shared__ __align__(16) float As[32][68];
    __shared__ __align__(16) float Ws[32][68];
    const int tid = threadIdx.x;
    const int tx = tid & 15, ty = tid >> 4;
    const int row0 = blockIdx.y << 6;
    const int col0 = blockIdx.x << 6;

    float acc[4][4] = {};

    for (int k0 = 0; k0 < K; k0 += 32) {
        #pragma unroll
        for (int s = 0; s < 2; ++s) {
            int f = tid + (s << 8);
            int rr = f >> 3;
            int kq = (f & 7) << 2;
            int k = k0 + kq;
            float4 v = make_float4(0.f, 0.f, 0.f, 0.f);
            size_t ro = (size_t)(row0 + rr) * (size_t)lda;
            if (Am) {
                if (k + 3 < K) {
                    float4 m = *(const float4*)(Am + ro + k);
                    float4 vv = *(const float4*)(Av + ro + k);
                    float4 e = *(const float4*)(Ae + ro + k);
                    v.x = fmaf(vv.x, e.x, m.x); v.y = fmaf(vv.y, e.y, m.y);
                    v.z = fmaf(vv.z, e.z, m.z); v.w = fmaf(vv.w, e.w, m.w);
                } else {
                    if (k + 0 < K) v.x = fmaf(Av[ro + k], Ae[ro + k], Am[ro + k]);
                    if (k + 1 < K) v.y = fmaf(Av[ro + k + 1], Ae[ro + k + 1], Am[ro + k + 1]);
                    if (k + 2 < K) v.z = fmaf(Av[ro + k + 2], Ae[ro + k + 2], Am[ro + k + 2]);
                }
            } else {
                const float* ap = A + ro;
                if (k + 3 < K) v = *(const float4*)(ap + k);
                else {
                    if (k + 0 < K) v.x = ap[k + 0];
                    if (k + 1 < K) v.y = ap[k + 1];
                    if (k + 2 < K) v.z = ap[k + 2];
                }
            }
            As[kq + 0][rr] = v.x; As[kq + 1][rr] = v.y;
            As[kq + 2][rr] = v.z; As[kq + 3][rr] = v.w;
        }
        #pragma unroll
        for (int s = 0; s < 2; ++s) {
            int f = tid + (s << 8);
            int rr = f >> 3;
            int kq = (f & 7) << 2;
            int k = k0 + kq;
            int n = col0 + rr;
            float4 v = make_float4(0.f, 0.f, 0.f, 0.f);
            if (n < N) {
                int nsrc = permW ? perm_src(n) : n;
                const float* wp = W + (size_t)nsrc * (size_t)ldw;
                if (k + 3 < K) v = *(const float4*)(wp + k);
                else {
                    if (k + 0 < K) v.x = wp[k + 0];
                    if (k + 1 < K) v.y = wp[k + 1];
                    if (k + 2 < K) v.z = wp[k + 2];
                }
            }
            Ws[kq + 0][rr] = v.x; Ws[kq + 1][rr] = v.y;
            Ws[kq + 2][rr] = v.z; Ws[kq + 3][rr] = v.w;
        }
        __syncthreads();
        #pragma unroll
        for (int k = 0; k < 32; ++k) {
            float4 av = *(const float4*)&As[k][ty << 2];
            float4 bv = *(const float4*)&Ws[k][tx << 2];
            acc[0][0] = fmaf(av.x, bv.x, acc[0][0]);
            acc[0][1] = fmaf(av.x, bv.y, acc[0][1]);
            acc[0][2] = fmaf(av.x, bv.z, acc[0][2]);
            acc[0][3] = fmaf(av.x, bv.w, acc[0][3]);
            acc[1][0] = fmaf(av.y, bv.x, acc[1][0]);
            acc[1][1] = fmaf(av.y, bv.y, acc[1][1]);
            acc[1][2] = fmaf(av.y, bv.z, acc[1][2]);
            acc[1][3] = fmaf(av.y, bv.w, acc[1][3]);
            acc[2][0] = fmaf(av.z, bv.x, acc[2][0]);
            acc[2][1] = fmaf(av.z, bv.y, acc[2][1]);
            acc[2][2] = fmaf(av.z, bv.z, acc[2][2]);
            acc[2][3] = fmaf(av.z, bv.w, acc[2][3]);
            acc[3][0] = fmaf(av.w, bv.x, acc[3][0]);
            acc[3][1] = fmaf(av.w, bv.y, acc[3][1]);
            acc[3][2] = fmaf(av.w, bv.z, acc[3][2]);
            acc[3][3] = fmaf(av.w, bv.w, acc[3][3]);
        }
        __syncthreads();
    }

    #pragma unroll
    for (int i = 0; i < 4; ++i) {
        int rr = row0 + (ty << 2) + i;
        float* cp = C + (size_t)rr * (size_t)ldc;
        #pragma unroll
        for (int j = 0; j < 4; ++j) {
            int cc = col0 + (tx << 2) + j;
            if (cc < N) {
                float v = acc[i][j];
                if (bias) v += bias[cc];
                if (relu) v = fmaxf(v, 0.f);
                cp[cc] = v;
            }
        }
    }
}

// ---------------------------------------------------------------------------
// One-shot packing: We, Wt (new layout), W1 (hi), E2 (hi/lo), biases.
// ---------------------------------------------------------------------------
#define N_WE (G4 * 608)
#define N_WT (G4 * 608)
#define N_W1 (256 * 512)
#define N_E2 (64 * 512)
__global__ void pack_all(
    u16* __restrict__ Weh, u16* __restrict__ Wel,
    u16* __restrict__ Wth, u16* __restrict__ Wtl,
    u16* __restrict__ W1h,
    u16* __restrict__ E2h, u16* __restrict__ E2l,
    float* __restrict__ be, float* __restrict__ ba, float* __restrict__ bt,
    const float* __restrict__ eWih, const float* __restrict__ eWhh,
    const float* __restrict__ tWih, const float* __restrict__ tWhh,
    const float* __restrict__ ts1W, const float* __restrict__ e2W,
    const float* __restrict__ ebih, const float* __restrict__ ebhh,
    const float* __restrict__ abih, const float* __restrict__ abhh,
    const float* __restrict__ tbih, const float* __restrict__ tbhh)
{
    int idx = blockIdx.x * 256 + threadIdx.x;
    if (idx < N_WE) {
        int np = idx / 608, k = idx - np * 608;
        int n = perm_src(np);
        float v = 0.f;
        if (k < 65) v = eWih[n * 65 + k];
        else if (k < 577) v = eWhh[(n << 9) + k - 65];
        u16 h = f2bf(v); Weh[idx] = h; Wel[idx] = f2bf(v - bf2f(h));
        return;
    }
    idx -= N_WE;
    if (idx < N_WT) {
        int np = idx / 608, k = idx - np * 608;
        int n = perm_src(np);
        float v = 0.f;
        if (k < 512) v = tWhh[(n << 9) + k];
        else if (k < 576) v = tWih[n * 585 + 520 + (k - 512)];
        else if (k == 576) v = tWih[n * 585 + 584];
        u16 h = f2bf(v); Wth[idx] = h; Wtl[idx] = f2bf(v - bf2f(h));
        return;
    }
    idx -= N_WT;
    if (idx < N_W1) {
        W1h[idx] = f2bf(ts1W[idx]);   // [256][512] row-major, hi only
        return;
    }
    idx -= N_W1;
    if (idx < N_E2) {
        float v = e2W[idx];           // [64][512] row-major
        u16 h = f2bf(v); E2h[idx] = h; E2l[idx] = f2bf(v - bf2f(h));
        return;
    }
    idx -= N_E2;
    if (idx < G4) {
        int n = perm_src(idx);
        be[idx] = ebih[n] + ebhh[n];
        ba[idx] = abih[n] + abhh[n];
        bt[idx] = tbih[n] + tbhh[n];
    }
}

__global__ void pack_wa(u16* __restrict__ hi, u16* __restrict__ lo,
                        const float* __restrict__ wih, const float* __restrict__ whh) {
    int idx = blockIdx.x * 256 + threadIdx.x;
    if (idx >= G4 * 576) return;
    int np = idx / 576, k = idx - np * 576;
    int n = perm_src(np);
    float v = (k < 64) ? wih[n * 584 + 520 + k] : whh[(n << 9) + k - 64];
    u16 h = f2bf(v); hi[idx] = h; lo[idx] = f2bf(v - bf2f(h));
}

// ---------------------------------------------------------------------------
// init_all: encoder X0/pads, c_e, lens, attr->tcat, decoder Xa0/Xt0, c_a, c_t.
// grid 512 x 256.
// ---------------------------------------------------------------------------
__global__ __launch_bounds__(256) void init_all(
    u16* __restrict__ xe0h, u16* __restrict__ xe0l,
    u16* __restrict__ xe1h, u16* __restrict__ xe1l,
    float* __restrict__ c_e, int* __restrict__ lens,
    float* __restrict__ tcat,
    u16* __restrict__ xa0h, u16* __restrict__ xa0l,
    u16* __restrict__ xt0h, u16* __restrict__ xt0l,
    float* __restrict__ c_a, float* __restrict__ c_t,
    const int* __restrict__ acts, const float* __restrict__ tsv,
    const float* __restrict__ act_emb,
    const int* __restrict__ attr_cat, const float* __restrict__ attr_num,
    const float* __restrict__ attr_emb,
    const float* __restrict__ a2aW, const float* __restrict__ a2ab)
{
    int b = blockIdx.x, tid = threadIdx.x;
    for (int j = tid; j < 608; j += 256) {
        float v = 0.f;
        if (j < 64) v = act_emb[acts[b << 6] * 64 + j];
        else if (j == 64) v = tsv[b << 6];
        u16 hh = f2bf(v);
        xe0h[b * 608 + j] = hh; xe0l[b * 608 + j] = f2bf(v - bf2f(hh));
        if (j >= 577) { xe1h[b * 608 + j] = 0; xe1l[b * 608 + j] = 0; }
    }
    for (int j = tid; j < CF; j += 256) {
        c_e[(b << 9) + j] = 0.f; c_a[(b << 9) + j] = 0.f; c_t[(b << 9) + j] = 0.f;
        xt0h[(b << 9) + j] = 0; xt0l[(b << 9) + j] = 0;
    }
    for (int j = tid; j < 576; j += 256) {
        float v = (j < 64) ? act_emb[63 * 64 + j] : 0.f;
        u16 hh = f2bf(v);
        xa0h[b * 576 + j] = hh; xa0l[b * 576 + j] = f2bf(v - bf2f(hh));
    }
    if (tid < 64) {
        int v = acts[(b << 6) + tid];
        int m = v;
        #pragma unroll
        for (int off = 32; off; off >>= 1) m = max(m, __shfl_xor(m, off));
        unsigned long long mask = __ballot(v == m);
        if (tid == 0) lens[b] = __ffsll(mask) - 1;
    }
    if (tid < 8) {
        const float* wr = a2aW + tid * 17;
        const float* em = attr_emb + attr_cat[b] * 16;
        float s = a2ab[tid];
        #pragma unroll
        for (int k = 0; k < 16; ++k) s = fmaf(em[k], wr[k], s);
        s = fmaf(attr_num[b], wr[16], s);
        tcat[b * TDIM + tid] = fmaxf(s, 0.f);
    }
}

__global__ __launch_bounds__(64) void attr_heads(
    const float* __restrict__ hid1, const float* __restrict__ hid2,
    const float* __restrict__ tc2W, const float* __restrict__ tc2b,
    const float* __restrict__ tn2W, const float* __restrict__ tn2b,
    float* __restrict__ out_cat, float* __restrict__ out_num) {
    __shared__ __align__(16) float h1[260], h2[260], sl[10];
    int b = blockIdx.x, tid = threadIdx.x;
    for (int k = tid; k < 260; k += 64) {
        h1[k] = hid1[b * 260 + k];
        h2[k] = hid2[b * 260 + k];
    }
    __syncthreads();
    if (tid < 10) {
        float l = tc2b[tid];
        const float* wr = tc2W + tid * 260;
        for (int k = 0; k < 260; ++k) l = fmaf(h1[k], wr[k], l);
        sl[tid] = l;
    }
    __syncthreads();
    if (tid < 10) {
        float m = sl[0];
        for (int i = 1; i < 10; ++i) m = fmaxf(m, sl[i]);
        float ssum = 0.f;
        for (int i = 0; i < 10; ++i) ssum += expf(sl[i] - m);
        out_cat[b * 10 + tid] = expf(sl[tid] - m) / ssum;
    }
    float p = 0.f;
    for (int k = tid; k < 260; k += 64) p = fmaf(h2[k], tn2W[k], p);
    #pragma unroll
    for (int off = 32; off; off >>= 1) p += __shfl_xor(p, off);
    if (tid == 0) out_num[b] = 1.f / (1.f + expf(-(p + tn2b[0])));
}

// ---------------------------------------------------------------------------
extern "C" void kernel_launch(void* const* d_in, const int* in_sizes, int n_in,
                              void* d_out, int out_size, void* d_ws, size_t ws_size,
                              hipStream_t stream) {
    const int*   attr_cat = (const int*)  d_in[0];
    const float* attr_num = (const float*)d_in[1];
    const int*   acts     = (const int*)  d_in[2];
    const float* tsv      = (const float*)d_in[3];
    const float* eps      = (const float*)d_in[4];
    const float* attr_emb = (const float*)d_in[5];
    const float* a2a_W    = (const float*)d_in[6];
    const float* a2a_b    = (const float*)d_in[7];
    const float* act_emb  = (const float*)d_in[8];
    const float* eWih     = (const float*)d_in[9];
    const float* eWhh     = (const float*)d_in[10];
    const float* ebih     = (const float*)d_in[11];
    const float* ebhh     = (const float*)d_in[12];
    const float* mean_W   = (const float*)d_in[13];
    const float* mean_b   = (const float*)d_in[14];
    const float* var_W    = (const float*)d_in[15];
    const float* var_b    = (const float*)d_in[16];
    const float* z2t_W    = (const float*)d_in[17];
    const float* z2t_b    = (const float*)d_in[18];
    const float* tc1_W    = (const float*)d_in[19];
    const float* tc1_b    = (const float*)d_in[20];
    const float* tc2_W    = (const float*)d_in[21];
    const float* tc2_b    = (const float*)d_in[22];
    const float* tn1_W    = (const float*)d_in[23];
    const float* tn1_b    = (const float*)d_in[24];
    const float* tn2_W    = (const float*)d_in[25];
    const float* tn2_b    = (const float*)d_in[26];
    const float* aWih     = (const float*)d_in[27];
    const float* aWhh     = (const float*)d_in[28];
    const float* abih     = (const float*)d_in[29];
    const float* abhh     = (const float*)d_in[30];
    const float* tWih     = (const float*)d_in[31];
    const float* tWhh     = (const float*)d_in[32];
    const float* tbih     = (const float*)d_in[33];
    const float* tbhh     = (const float*)d_in[34];
    const float* e2act_W  = (const float*)d_in[35];
    const float* e2act_b  = (const float*)d_in[36];
    const float* ts1_W    = (const float*)d_in[37];
    const float* ts1_b    = (const float*)d_in[38];
    const float* ts2_W    = (const float*)d_in[39];
    const float* ts2_b    = (const float*)d_in[40];

    float* out = (float*)d_out;
    float* out_cat  = out;
    float* out_num  = out + 5120;
    float* out_acts = out + 5632;
    float* out_ts   = out + 2102784;
    float* outm     = out + 2135552;
    float* outv     = out + 2201088;

    char* w = (char*)d_ws;
    auto alloc = [&](size_t bytes) { char* p = w; w += (bytes + 255) & ~(size_t)255; return p; };
    // --- persistent region ---
    u16*   Wt_hi  = (u16*)alloc((size_t)G4 * 608 * 2);
    u16*   Wt_lo  = (u16*)alloc((size_t)G4 * 608 * 2);
    u16*   W1h    = (u16*)alloc(256 * 512 * 2);
    u16*   E2h    = (u16*)alloc(64 * 512 * 2);
    u16*   E2l    = (u16*)alloc(64 * 512 * 2);
    float* bias_e = (float*)alloc(G4 * 4);
    float* bias_a = (float*)alloc(G4 * 4);
    float* bias_t = (float*)alloc(G4 * 4);
    float* base_a = (float*)alloc((size_t)B * G4 * 4);
    float* base_t = (float*)alloc((size_t)B * G4 * 4);
    u16*   Xa_hi  = (u16*)alloc((size_t)2 * B * 576 * 2);
    u16*   Xa_lo  = (u16*)alloc((size_t)2 * B * 576 * 2);
    u16*   Xt_hi  = (u16*)alloc((size_t)2 * B * 512 * 2);
    u16*   Xt_lo  = (u16*)alloc((size_t)2 * B * 512 * 2);
    float* c_a    = (float*)alloc((size_t)B * CF * 4);
    float* c_t    = (float*)alloc((size_t)B * CF * 4);
    float* tcat   = (float*)alloc((size_t)B * TDIM * 4);
    float* t_rec  = (float*)alloc((size_t)B * TDIM * 4);
    float* hid1   = (float*)alloc((size_t)B * 260 * 4);
    float* hid2   = (float*)alloc((size_t)B * 260 * 4);
    int*   lens   = (int*)alloc(512 * 4);
    float* ts_val = (float*)alloc(512 * 4);
    // --- phase overlay: encoder {We,Xe,c_e} / decoder {Wa} ---
    char* phase = w;
    u16*   We_hi  = (u16*)(phase);
    u16*   We_lo  = (u16*)(phase + (size_t)G4 * 608 * 2);
    u16*   Xe_hi  = (u16*)(phase + (size_t)2 * G4 * 608 * 2);
    u16*   Xe_lo  = (u16*)(phase + (size_t)2 * G4 * 608 * 2 + (size_t)2 * B * 608 * 2);
    float* c_e    = (float*)(phase + (size_t)2 * G4 * 608 * 2 + (size_t)4 * B * 608 * 2);
    u16*   Wa_hi  = (u16*)(phase);
    u16*   Wa_lo  = (u16*)(phase + (size_t)G4 * 576 * 2);
    (void)ws_size; (void)in_sizes; (void)n_in; (void)out_size;

    // ---- prep (2 launches) ----
    {
        int total = N_WE + N_WT + N_W1 + N_E2 + G4;
        pack_all<<<(total + 255) / 256, 256, 0, stream>>>(
            We_hi, We_lo, Wt_hi, Wt_lo, W1h, E2h, E2l,
            bias_e, bias_a, bias_t,
            eWih, eWhh, tWih, tWhh, ts1_W, e2act_W,
            ebih, ebhh, abih, abhh, tbih, tbhh);
    }
    init_all<<<B, 256, 0, stream>>>(
        Xe_hi, Xe_lo, Xe_hi + (size_t)B * 608, Xe_lo + (size_t)B * 608,
        c_e, lens, tcat,
        Xa_hi, Xa_lo, Xt_hi, Xt_lo, c_a, c_t,
        acts, tsv, act_emb, attr_cat, attr_num, attr_emb, a2a_W, a2a_b);

    // ---- encoder (64 launches) ----
    for (int t = 0; t < TT; ++t) {
        const u16* xh = Xe_hi + (size_t)(t & 1) * B * 608;
        const u16* xl = Xe_lo + (size_t)(t & 1) * B * 608;
        u16* xnh = Xe_hi + (size_t)((t + 1) & 1) * B * 608;
        u16* xnl = Xe_lo + (size_t)((t + 1) & 1) * B * 608;
        enc_step<<<dim3(32, 8), 256, 0, stream>>>(
            xh, xl, We_hi, We_lo, bias_e, c_e, xnh, xnl,
            tcat, lens, acts, tsv, act_emb, t);
    }

    // ---- decoder weight pack (overlays We after encoder) ----
    pack_wa<<<(G4 * 576 + 255) / 256, 256, 0, stream>>>(Wa_hi, Wa_lo, aWih, aWhh);

    // ---- latent (5 launches) ----
    gemm_tn<<<dim3(2, 8, 2), 256, 0, stream>>>(
        tcat, nullptr, nullptr, nullptr, TDIM, mean_W, TDIM, var_W, TDIM,
        ZD, TDIM, mean_b, var_b, outm, outv, ZD, 0, 0);
    gemm_tn<<<dim3(9, 8, 1), 256, 0, stream>>>(
        nullptr, outm, outv, eps, ZD, z2t_W, ZD, nullptr, 0,
        TDIM, ZD, z2t_b, nullptr, t_rec, nullptr, TDIM, 1, 0);
    gemm_tn<<<dim3(5, 8, 2), 256, 0, stream>>>(
        t_rec, nullptr, nullptr, nullptr, TDIM, tc1_W, TDIM, tn1_W, TDIM,
        260, TDIM, tc1_b, tn1_b, hid1, hid2, 260, 1, 0);
    attr_heads<<<B, 64, 0, stream>>>(hid1, hid2, tc2_W, tc2_b, tn2_W, tn2_b, out_cat, out_num);
    gemm_tn<<<dim3(32, 8, 2), 256, 0, stream>>>(
        t_rec, nullptr, nullptr, nullptr, TDIM, aWih, 584, tWih, 585,
        G4, TDIM, bias_a, bias_t, base_a, base_t, G4, 0, 1);

    // ---- decoder (128 launches + tail) ----
    for (int t = 0; t < TT; ++t) {
        u16* xah  = Xa_hi + (size_t)(t & 1) * B * 576;
        u16* xal  = Xa_lo + (size_t)(t & 1) * B * 576;
        u16* xanh = Xa_hi + (size_t)((t + 1) & 1) * B * 576;
        u16* xanl = Xa_lo + (size_t)((t + 1) & 1) * B * 576;
        u16* xth  = Xt_hi + (size_t)(t & 1) * B * 512;
        u16* xtl  = Xt_lo + (size_t)(t & 1) * B * 512;
        u16* xtnh = Xt_hi + (size_t)((t + 1) & 1) * B * 512;
        u16* xtnl = Xt_lo + (size_t)((t + 1) & 1) * B * 512;

        dec_k1<<<dim3(32, 8), 256, 0, stream>>>(
            xah, xal, xanh, xanl, Wa_hi, Wa_lo, base_a, c_a,
            xth, xtl, W1h, ts1_b, ts2_W, ts2_b, ts_val, out_ts, t);
        dec_k2<<<dim3(32, 8), 256, 0, stream>>>(
            xanh, xanl, E2h, E2l, e2act_b, act_emb, out_acts,
            Wt_hi, Wt_lo, base_t, c_t, xth, xtl, xtnh, xtnl, ts_val, t);
    }
    ts_tail<<<dim3(1, 8), 256, 0, stream>>>(
        Xt_hi, Xt_lo, W1h, ts1_b, ts2_W, ts2_b, out_ts);
}